// Round 7
// baseline (123.847 us; speedup 1.0000x reference)
//
#include <hip/hip_runtime.h>

typedef float f32x4 __attribute__((ext_vector_type(4)));
typedef __bf16 bf16x8 __attribute__((ext_vector_type(8)));
typedef unsigned short u16x8 __attribute__((ext_vector_type(8)));

#define D_DIM 128
#define SCALE  1.2011224087864498f   // sqrt(log2(e)): both operands scaled -> acc = log2e * sim
#define LN2    0.6931471805599453f
#define E1F    2.7182818284590452f

// fp32 -> bf16 round-to-nearest-even
static __device__ __forceinline__ unsigned short f2bf(float f) {
    unsigned u = __float_as_uint(f);
    u += 0x7fffu + ((u >> 16) & 1u);
    return (unsigned short)(u >> 16);
}

static __device__ __forceinline__ void gload_lds16(const unsigned short* gsrc, void* lds_dst) {
    auto gp = (const __attribute__((address_space(1))) unsigned int*)gsrc;
    auto lp = (__attribute__((address_space(3))) unsigned int*)(unsigned int)(unsigned long long)lds_dst;
    __builtin_amdgcn_global_load_lds(gp, lp, 16, 0, 0);
}

// ---------------------------------------------------------------------------
// prep: normalize rows (scaled by sqrt(log2e)), store A in MFMA-fragment
// order. Fragment f = jtile*4 + kb is 1 KB: lane l holds row jtile*16+(l&15),
// k = kb*32 + (l>>4)*8 .. +7. Row-norm reduce = shfl_xor over the 4 lanes
// sharing (l&15). Also: class column-sums C[256] (global atomics), count n0.
__global__ __launch_bounds__(256) void prep_kernel(const float* __restrict__ X,
                                                   const int* __restrict__ labels,
                                                   unsigned short* __restrict__ P,
                                                   float* __restrict__ C,
                                                   int* __restrict__ n0) {
    int tid = threadIdx.x, wave = tid >> 6, lane = tid & 63;
    int l15 = lane & 15, lhi = lane >> 4;
    int jtile = blockIdx.x * 4 + wave;
    int row = jtile * 16 + l15;

    float v[4][8];
    float ss = 0.f;
    #pragma unroll
    for (int kb = 0; kb < 4; ++kb) {
        const float4* xp = reinterpret_cast<const float4*>(X + (size_t)row * D_DIM + kb * 32 + lhi * 8);
        float4 a = xp[0], b = xp[1];
        v[kb][0] = a.x; v[kb][1] = a.y; v[kb][2] = a.z; v[kb][3] = a.w;
        v[kb][4] = b.x; v[kb][5] = b.y; v[kb][6] = b.z; v[kb][7] = b.w;
        ss += a.x*a.x + a.y*a.y + a.z*a.z + a.w*a.w
            + b.x*b.x + b.y*b.y + b.z*b.z + b.w*b.w;
    }
    ss += __shfl_xor(ss, 16);
    ss += __shfl_xor(ss, 32);
    float rn = rsqrtf(ss) * SCALE;
    bool is0 = (labels[row] == 0);

    #pragma unroll
    for (int kb = 0; kb < 4; ++kb) {
        u16x8 o;
        #pragma unroll
        for (int e = 0; e < 8; ++e) { v[kb][e] *= rn; o[e] = f2bf(v[kb][e]); }
        *reinterpret_cast<u16x8*>(P + ((size_t)jtile * 4 + kb) * 512 + lane * 8) = o;
    }

    // class column-sums via LDS, then one global atomic per slot
    __shared__ float CL[256];
    CL[tid] = 0.f;
    __syncthreads();
    int cbase = is0 ? 0 : 128;
    #pragma unroll
    for (int kb = 0; kb < 4; ++kb)
        #pragma unroll
        for (int e = 0; e < 8; ++e)
            atomicAdd(&CL[cbase + kb * 32 + lhi * 8 + e], v[kb][e]);
    __syncthreads();
    atomicAdd(&C[tid], CL[tid]);

    // class-0 count: one lane per row (lhi==0)
    unsigned long long b = __ballot(is0 && lhi == 0);
    if (lane == 0) atomicAdd(n0, (int)__popcll(b));
}

// ---------------------------------------------------------------------------
// main: S1part[split][i] = sum_{j in split} exp(sim_ij); split = 128 cols.
// Stage the block's entire B-slice (8 tiles x 4 frags = 32 KB) into LDS ONCE
// via global_load_lds (packed layout: global src and LDS dest both linear,
// lane*16B ds_read_b128 is conflict-free). ONE barrier; the 8-tile j-loop is
// fully unrolled, LDS-only, register-double-buffered, no in-loop barriers.
__global__ __launch_bounds__(256) void main_kernel(const unsigned short* __restrict__ Pk,
                                                   float* __restrict__ S1part,
                                                   int N) {
    __shared__ unsigned short Bs[16384];   // 32 KB = 32 fragments
    int tid = threadIdx.x, wave = tid >> 6, lane = tid & 63;
    int l15 = lane & 15, lhi = lane >> 4;
    int m0 = blockIdx.x * 256 + wave * 64;
    int split = blockIdx.y;
    const int TILES = 8;                   // jlen = 128 cols per split
    int t0 = split * TILES;

    // stage: wave w copies fragments w*8 .. w*8+7 (1 KB each)
    #pragma unroll
    for (int f = 0; f < 8; ++f) {
        int frag = wave * 8 + f;
        gload_lds16(Pk + (((size_t)(t0 * 4 + frag)) << 9) + lane * 8,
                    (char*)Bs + frag * 1024);
    }

    // A fragments from global (arrive under the staging barrier)
    const u16x8* P = reinterpret_cast<const u16x8*>(Pk);
    int fa0 = (m0 >> 4) << 2;
    bf16x8 af[4][4];
    #pragma unroll
    for (int ms = 0; ms < 4; ++ms)
        #pragma unroll
        for (int kb = 0; kb < 4; ++kb)
            af[ms][kb] = __builtin_bit_cast(bf16x8, P[(size_t)(fa0 + ms * 4 + kb) * 64 + lane]);

    float s1[4][4];
    #pragma unroll
    for (int ms = 0; ms < 4; ++ms)
        #pragma unroll
        for (int r = 0; r < 4; ++r) s1[ms][r] = 0.f;

    __syncthreads();   // drains staging vmcnt; only barrier in the kernel

    const char* BsB = (const char*)Bs;
    bf16x8 bA[4], bB[4];
    #pragma unroll
    for (int kb = 0; kb < 4; ++kb)
        bA[kb] = *reinterpret_cast<const bf16x8*>(BsB + kb * 1024 + lane * 16);

    #pragma unroll
    for (int t = 0; t < TILES; t += 2) {
        #pragma unroll
        for (int kb = 0; kb < 4; ++kb)
            bB[kb] = *reinterpret_cast<const bf16x8*>(BsB + ((t + 1) * 4 + kb) * 1024 + lane * 16);
        {
            f32x4 acc[4] = {{0,0,0,0},{0,0,0,0},{0,0,0,0},{0,0,0,0}};
            #pragma unroll
            for (int kb = 0; kb < 4; ++kb)
                #pragma unroll
                for (int ms = 0; ms < 4; ++ms)
                    acc[ms] = __builtin_amdgcn_mfma_f32_16x16x32_bf16(af[ms][kb], bA[kb], acc[ms], 0, 0, 0);
            #pragma unroll
            for (int ms = 0; ms < 4; ++ms)
                #pragma unroll
                for (int r = 0; r < 4; ++r)
                    s1[ms][r] += __builtin_amdgcn_exp2f(acc[ms][r]);
        }
        if (t + 2 < TILES) {
            #pragma unroll
            for (int kb = 0; kb < 4; ++kb)
                bA[kb] = *reinterpret_cast<const bf16x8*>(BsB + ((t + 2) * 4 + kb) * 1024 + lane * 16);
        }
        {
            f32x4 acc[4] = {{0,0,0,0},{0,0,0,0},{0,0,0,0},{0,0,0,0}};
            #pragma unroll
            for (int kb = 0; kb < 4; ++kb)
                #pragma unroll
                for (int ms = 0; ms < 4; ++ms)
                    acc[ms] = __builtin_amdgcn_mfma_f32_16x16x32_bf16(af[ms][kb], bB[kb], acc[ms], 0, 0, 0);
            #pragma unroll
            for (int ms = 0; ms < 4; ++ms)
                #pragma unroll
                for (int r = 0; r < 4; ++r)
                    s1[ms][r] += __builtin_amdgcn_exp2f(acc[ms][r]);
        }
    }

    // reduce over the 16 l15-lanes holding the same rows
    #pragma unroll
    for (int m = 1; m < 16; m <<= 1)
        #pragma unroll
        for (int ms = 0; ms < 4; ++ms)
            #pragma unroll
            for (int r = 0; r < 4; ++r)
                s1[ms][r] += __shfl_xor(s1[ms][r], m);
    if (l15 == 0) {
        #pragma unroll
        for (int ms = 0; ms < 4; ++ms)
            #pragma unroll
            for (int r = 0; r < 4; ++r)
                S1part[(size_t)split * N + m0 + ms * 16 + lhi * 4 + r] = s1[ms][r];
    }
}

// ---------------------------------------------------------------------------
// finish: per row S1 = sum of split partials; Lc = sum_{i in c} log(S1_i - e).
// Pos-pair sums via identity: sum_{i in c} sum_{pos j} sim_ij = ||C_c||^2 - n_c.
// Block partials -> scal atomics; last block (counter) computes the loss.
__global__ __launch_bounds__(256) void finish_kernel(const float* __restrict__ S1part,
                                                     const float* __restrict__ C,
                                                     const int* __restrict__ labels,
                                                     int* __restrict__ n0p,
                                                     float* __restrict__ scal,
                                                     int* __restrict__ counter,
                                                     float* __restrict__ out,
                                                     int N, int nsplit) {
    int tid = threadIdx.x, wave = tid >> 6, lane = tid & 63;
    int row = blockIdx.x * 256 + tid;

    float S1 = 0.f;
    for (int s = 0; s < nsplit; ++s) S1 += S1part[(size_t)s * N + row];
    bool is0 = (labels[row] == 0);
    float lg = __builtin_amdgcn_logf(S1 - E1F) * LN2;   // natural log of denom
    float v0 = is0 ? lg : 0.f, v1 = is0 ? 0.f : lg;
    #pragma unroll
    for (int m = 1; m < 64; m <<= 1) { v0 += __shfl_xor(v0, m); v1 += __shfl_xor(v1, m); }

    __shared__ float red[4][2];
    __shared__ int isLast;
    if (lane == 0) { red[wave][0] = v0; red[wave][1] = v1; }
    __syncthreads();
    if (tid == 0) {
        atomicAdd(&scal[0], red[0][0] + red[1][0] + red[2][0] + red[3][0]);
        atomicAdd(&scal[1], red[0][1] + red[1][1] + red[2][1] + red[3][1]);
        __threadfence();
        int old = atomicAdd(counter, 1);
        isLast = (old == (int)gridDim.x - 1) ? 1 : 0;
    }
    __syncthreads();
    if (isLast) {
        // tid<128 = class0 columns, tid>=128 = class1 (waves 0,1 vs 2,3)
        float c = C[tid];
        float sq = c * c;
        #pragma unroll
        for (int m = 1; m < 64; m <<= 1) sq += __shfl_xor(sq, m);
        __shared__ float sqred[4];
        if (lane == 0) sqred[wave] = sq;
        __syncthreads();
        if (tid == 0) {
            float C0sq = (sqred[0] + sqred[1]) * LN2;   // un-scale: SCALE^2 = log2e
            float C1sq = (sqred[2] + sqred[3]) * LN2;
            float L0 = atomicAdd(&scal[0], 0.f);
            float L1 = atomicAdd(&scal[1], 0.f);
            int   n0 = atomicAdd(n0p, 0);
            float fn0 = (float)n0, fn1 = (float)(N - n0);
            float P0 = C0sq - fn0, P1 = C1sq - fn1;
            out[0] = ((fn0 - 1.f) * L0 - P0) / fn0 + (fn1 - 1.f) * L1 - P1;
        }
    }
}

// ---------------------------------------------------------------------------
extern "C" void kernel_launch(void* const* d_in, const int* in_sizes, int n_in,
                              void* d_out, int out_size, void* d_ws, size_t ws_size,
                              hipStream_t stream) {
    (void)n_in; (void)out_size; (void)ws_size;
    const float* X      = (const float*)d_in[0];
    const int*   labels = (const int*)d_in[1];
    int N = in_sizes[1];                       // 8192; assumes D=128, N % 256 == 0
    int nsplit = N / 128;                      // 64: each split = 128 cols = 32 KB LDS

    char* ws = (char*)d_ws;
    unsigned short* A_pack  = (unsigned short*)ws;                              // 2 MB
    float*          S1part  = (float*)(ws + (size_t)N * D_DIM * 2);             // 2 MB
    float*          C       = (float*)((char*)S1part + (size_t)nsplit * N * 4); // 1 KB
    float*          scal    = (float*)((char*)C + 1024);                        // 8 B
    int*            n0      = (int*)((char*)scal + 8);
    int*            counter = n0 + 1;
    float*          out     = (float*)d_out;

    hipMemsetAsync(C, 0, 1024 + 8 + 4 + 4, stream);

    prep_kernel<<<N / 64, 256, 0, stream>>>(X, labels, A_pack, C, n0);

    dim3 grid(N / 256, nsplit);
    main_kernel<<<grid, 256, 0, stream>>>(A_pack, S1part, N);

    finish_kernel<<<N / 256, 256, 0, stream>>>(S1part, C, labels, n0, scal, counter, out, N, nsplit);
}